// Round 5
// baseline (124.610 us; speedup 1.0000x reference)
//
#include <hip/hip_runtime.h>
#include <hip/hip_bf16.h>
#include <math.h>

typedef _Float16 f16x8 __attribute__((ext_vector_type(8)));
typedef _Float16 f16x4 __attribute__((ext_vector_type(4)));
typedef float f32x4 __attribute__((ext_vector_type(4)));

#define LDH 264  // 256 + 8 f16 pad -> row stride 132 dwords (4-bank rotation):
                 // b128 reads and 16B-lane writes are bank-balanced, no swizzle

// ---------------- A/B projection: A = xf @ W1[:258] + b1, B = xf @ W1[258:] ----
__global__ void prep_ab(const float* __restrict__ x, const float* __restrict__ W1,
                        const float* __restrict__ b1,
                        float* __restrict__ A, float* __restrict__ B) {
    int blk = blockIdx.x;
    int bs = blk >> 2, pg = blk & 3;           // 4 p-values per block
    __shared__ float xs[258 * 4];              // [c][pp]
    for (int i = threadIdx.x; i < 1024; i += 512) {
        int c = i >> 2, pp = i & 3;
        xs[i] = x[bs * 4096 + c * 16 + pg * 4 + pp];
    }
    if (threadIdx.x < 8) {
        int pp = threadIdx.x & 3, c = 256 + (threadIdx.x >> 2);
        int p = pg * 4 + pp;
        xs[c * 4 + pp] = (float)((c == 256) ? (p >> 2) : (p & 3)) * 0.25f;
    }
    __syncthreads();
    int half = threadIdx.x >> 8;               // 0 -> A, 1 -> B
    int col  = threadIdx.x & 255;
    float acc[4] = {0.f, 0.f, 0.f, 0.f};
    const float* Wp = W1 + half * 258 * 256 + col;
    for (int c = 0; c < 258; c++) {
        float w = Wp[c * 256];
#pragma unroll
        for (int pp = 0; pp < 4; pp++) acc[pp] += xs[c * 4 + pp] * w;
    }
    float* out = half ? B : A;
    float bias = half ? 0.f : b1[col];         // fold b1 into A once
#pragma unroll
    for (int pp = 0; pp < 4; pp++)
        out[(bs * 16 + pg * 4 + pp) * 256 + col] = acc[pp] + bias;
}

// ---- W2/W3/W4 -> f16 fragment-contiguous layout: flat = frag*512 + lane*8 + e --
// frag = (L*16 + cg)*8 + kk ; col = cg*16 + (lane&15) ; k = kk*32 + (lane>>4)*8 + e
__global__ void prep_w(const float* __restrict__ W2, const float* __restrict__ W3,
                       const float* __restrict__ W4, _Float16* __restrict__ Wt) {
    int blk = blockIdx.x;                      // = frag index, 0..383
    int t   = threadIdx.x;                     // 0..511 = lane*8 + e
    int kk = blk & 7, cg = (blk >> 3) & 15, L = blk >> 7;
    int l = t >> 3, e = t & 7;
    int col = cg * 16 + (l & 15);
    int k   = kk * 32 + (l >> 4) * 8 + e;
    const float* W = (L == 0) ? W2 : (L == 1) ? W3 : W4;
    Wt[blk * 512 + t] = (_Float16)W[k * 256 + col];
}

// ---------------- the big fused kernel ------------------------------------------
// grid 1600 = (b,s1,s2) x 2 row-halves; 512 threads = 8 waves, each 64r x 64c
// single in-place LDS h buffer 128 x LDH (67.6 KB) -> 2 blocks/CU = 16 waves/CU
__global__ __launch_bounds__(512, 4) void pairnet(
        const float* __restrict__ A, const float* __restrict__ B,
        const _Float16* __restrict__ Wt,
        const float* __restrict__ b2, const float* __restrict__ b3,
        const float* __restrict__ b4, float* __restrict__ pooled4) {
    __shared__ _Float16 hb[128 * LDH];         // 67.6 KB

    int blk  = blockIdx.x;
    int half = blk & 1;
    int bss  = blk >> 1;                       // (b*20+s1)*20+s2
    int s2   = bss % 20;
    int s1   = (bss / 20) % 20;
    int b    = bss / 400;
    int tid  = threadIdx.x;

    // ---- layer 1: h1 = relu(A[b,s2,p2] + B[b,s1,p1]), fp32 -> f16 into hb ----
    // 8-col units: each thread writes 16B (b128) -> all 32 banks covered
    const float* Abase = A + (b * 20 + s2) * 16 * 256;
    const float* Bbase = B + ((b * 20 + s1) * 16 + half * 8) * 256;
#pragma unroll
    for (int it = 0; it < 8; it++) {
        int u = it * 512 + tid;            // 0..4095 8-col units
        int r = u >> 5;                    // row 0..127 (= p1loc*16 + p2)
        int c = (u & 31) * 8;              // col
        const float* Ap = Abase + (r & 15) * 256 + c;
        const float* Bp = Bbase + (r >> 4) * 256 + c;
        float4 a0 = *(const float4*)(Ap);
        float4 a1 = *(const float4*)(Ap + 4);
        float4 b0 = *(const float4*)(Bp);
        float4 b1 = *(const float4*)(Bp + 4);
        f16x8 hv;
        hv[0] = (_Float16)fmaxf(a0.x + b0.x, 0.f);
        hv[1] = (_Float16)fmaxf(a0.y + b0.y, 0.f);
        hv[2] = (_Float16)fmaxf(a0.z + b0.z, 0.f);
        hv[3] = (_Float16)fmaxf(a0.w + b0.w, 0.f);
        hv[4] = (_Float16)fmaxf(a1.x + b1.x, 0.f);
        hv[5] = (_Float16)fmaxf(a1.y + b1.y, 0.f);
        hv[6] = (_Float16)fmaxf(a1.z + b1.z, 0.f);
        hv[7] = (_Float16)fmaxf(a1.w + b1.w, 0.f);
        *(f16x8*)(hb + r * LDH + c) = hv;
    }
    __syncthreads();

    int wid = tid >> 6, lane = tid & 63;
    int row0 = (wid >> 2) * 64;            // wave owns 64 rows x 64 cols
    int col0 = (wid & 3) * 64;
    int lr = lane & 15, lk = lane >> 4;

#pragma unroll
    for (int L = 0; L < 3; L++) {
        const float* bias = (L == 0) ? b2 : (L == 1) ? b3 : b4;
        // fragment-contiguous W base for this wave's 4 col-groups
        const _Float16* wb = Wt + (size_t)((L * 16 + (wid & 3) * 4) * 8) * 512 + lane * 8;

        f32x4 acc[4][4];
#pragma unroll
        for (int m = 0; m < 4; m++)
#pragma unroll
            for (int n = 0; n < 4; n++) acc[m][n] = (f32x4){0.f, 0.f, 0.f, 0.f};

#pragma unroll
        for (int kk = 0; kk < 8; kk++) {
            f16x8 w[4], a[4];
#pragma unroll
            for (int n = 0; n < 4; n++)
                w[n] = *(const f16x8*)(wb + (n * 8 + kk) * 512);
#pragma unroll
            for (int m = 0; m < 4; m++)
                a[m] = *(const f16x8*)(hb + (row0 + 16 * m + lr) * LDH + kk * 32 + 8 * lk);
            // swapped operands -> transposed D: thread holds row row0+16m+lr,
            // cols col0+16n+4lk+{0..3}
#pragma unroll
            for (int m = 0; m < 4; m++)
#pragma unroll
                for (int n = 0; n < 4; n++)
                    acc[m][n] = __builtin_amdgcn_mfma_f32_16x16x32_f16(
                        w[n], a[m], acc[m][n], 0, 0, 0);
        }

        if (L < 2) {
            __syncthreads();               // all reads of hb complete
#pragma unroll
            for (int n = 0; n < 4; n++) {
                int cb = col0 + 16 * n + 4 * lk;
                float4 b4v = *(const float4*)(bias + cb);
#pragma unroll
                for (int m = 0; m < 4; m++) {
                    int row = row0 + 16 * m + lr;
                    f16x4 hv;
                    hv[0] = (_Float16)fmaxf(acc[m][n][0] + b4v.x, 0.f);
                    hv[1] = (_Float16)fmaxf(acc[m][n][1] + b4v.y, 0.f);
                    hv[2] = (_Float16)fmaxf(acc[m][n][2] + b4v.z, 0.f);
                    hv[3] = (_Float16)fmaxf(acc[m][n][3] + b4v.w, 0.f);
                    *(f16x4*)(hb + row * LDH + cb) = hv;
                }
            }
            __syncthreads();               // writes visible
        } else {
            // layer 4: bias+relu, pool wave's 64 rows (m in-thread, lr butterfly)
#pragma unroll
            for (int n = 0; n < 4; n++) {
                int cb = col0 + 16 * n + 4 * lk;
                float4 b4v = *(const float4*)(bias + cb);
                f32x4 s = (f32x4){0.f, 0.f, 0.f, 0.f};
#pragma unroll
                for (int m = 0; m < 4; m++) {
                    s[0] += fmaxf(acc[m][n][0] + b4v.x, 0.f);
                    s[1] += fmaxf(acc[m][n][1] + b4v.y, 0.f);
                    s[2] += fmaxf(acc[m][n][2] + b4v.z, 0.f);
                    s[3] += fmaxf(acc[m][n][3] + b4v.w, 0.f);
                }
#pragma unroll
                for (int mask = 1; mask <= 8; mask <<= 1) {
#pragma unroll
                    for (int c = 0; c < 4; c++) s[c] += __shfl_xor(s[c], mask);
                }
                if (lr == 0) {
                    int slab = half * 2 + (wid >> 2);
                    float4 sv; sv.x = s[0]; sv.y = s[1]; sv.z = s[2]; sv.w = s[3];
                    *(float4*)(pooled4 + ((size_t)slab * 800 + bss) * 256 + cb) = sv;
                }
            }
        }
    }
}

// ---------------- final MLP on pooled [800,256] (sums 4 slabs) ------------------
__global__ void final_mlp(const float* __restrict__ pooled4,
        const float* __restrict__ Wf1, const float* __restrict__ bf1,
        const float* __restrict__ Wf2, const float* __restrict__ bf2,
        const float* __restrict__ Wf3, const float* __restrict__ bf3,
        const float* __restrict__ Wf4, const float* __restrict__ bf4,
        float* __restrict__ out) {
    __shared__ float p[4][256], y[4][256], z[4][256], y3[4][29];
    int r0 = blockIdx.x * 4;
    int t  = threadIdx.x;
    for (int i = t; i < 1024; i += 256) {
        int r = i >> 8, c = i & 255;
        float v = 0.f;
#pragma unroll
        for (int q = 0; q < 4; q++)
            v += pooled4[((size_t)q * 800 + r0 + r) * 256 + c];
        p[r][c] = v;
    }
    __syncthreads();
    float acc[4];
#pragma unroll
    for (int r = 0; r < 4; r++) acc[r] = bf1[t];
    for (int k = 0; k < 256; k++) {
        float w = Wf1[k * 256 + t];
#pragma unroll
        for (int r = 0; r < 4; r++) acc[r] += p[r][k] * w;
    }
#pragma unroll
    for (int r = 0; r < 4; r++) y[r][t] = fmaxf(acc[r], 0.f);
    __syncthreads();
#pragma unroll
    for (int r = 0; r < 4; r++) acc[r] = bf2[t];
    for (int k = 0; k < 256; k++) {
        float w = Wf2[k * 256 + t];
#pragma unroll
        for (int r = 0; r < 4; r++) acc[r] += y[r][k] * w;
    }
#pragma unroll
    for (int r = 0; r < 4; r++) z[r][t] = fmaxf(acc[r], 0.f);
    __syncthreads();
    if (t < 116) {
        int r = t / 29, c = t % 29;
        float a = bf3[c];
        for (int k = 0; k < 256; k++) a += z[r][k] * Wf3[k * 29 + c];
        y3[r][c] = fmaxf(a, 0.f);
    }
    __syncthreads();
    if (t < 4) {
        float zz = bf4[0];
#pragma unroll
        for (int c = 0; c < 29; c++) zz += y3[t][c] * Wf4[c];
        out[r0 + t] = 1.f / (1.f + expf(-zz));
    }
}

extern "C" void kernel_launch(void* const* d_in, const int* in_sizes, int n_in,
                              void* d_out, int out_size, void* d_ws, size_t ws_size,
                              hipStream_t stream) {
    const float* x   = (const float*)d_in[0];
    const float* W1  = (const float*)d_in[1];
    const float* b1  = (const float*)d_in[2];
    const float* W2  = (const float*)d_in[3];
    const float* b2  = (const float*)d_in[4];
    const float* W3  = (const float*)d_in[5];
    const float* b3  = (const float*)d_in[6];
    const float* W4  = (const float*)d_in[7];
    const float* b4  = (const float*)d_in[8];
    const float* Wf1 = (const float*)d_in[9];
    const float* bf1 = (const float*)d_in[10];
    const float* Wf2 = (const float*)d_in[11];
    const float* bf2 = (const float*)d_in[12];
    const float* Wf3 = (const float*)d_in[13];
    const float* bf3 = (const float*)d_in[14];
    const float* Wf4 = (const float*)d_in[15];
    const float* bf4 = (const float*)d_in[16];

    float* A       = (float*)d_ws;                     // 640*256 f32
    float* B       = A + 640 * 256;                    // 640*256 f32
    float* pooled4 = B + 640 * 256;                    // 4*800*256 f32
    _Float16* Wt   = (_Float16*)(pooled4 + 4 * 800 * 256); // 384 frags * 512 f16

    prep_ab<<<160, 512, 0, stream>>>(x, W1, b1, A, B);
    prep_w<<<384, 512, 0, stream>>>(W2, W3, W4, Wt);
    pairnet<<<1600, 512, 0, stream>>>(A, B, Wt, b2, b3, b4, pooled4);
    final_mlp<<<200, 256, 0, stream>>>(pooled4, Wf1, bf1, Wf2, bf2, Wf3, bf3, Wf4, bf4,
                                       (float*)d_out);
}